// Round 2
// baseline (1902.500 us; speedup 1.0000x reference)
//
#include <hip/hip_runtime.h>
#include <math.h>

#define NB 32768
#define KC 4096
#define DD 512
#define DELTA 4.0f

typedef __attribute__((ext_vector_type(8))) short short8;
typedef __attribute__((ext_vector_type(4))) float f32x4;

__device__ __forceinline__ unsigned short f2bf(float f) {
    unsigned u = __float_as_uint(f);
    u += 0x7FFFu + ((u >> 16) & 1u);     // RNE truncate to bf16
    return (unsigned short)(u >> 16);
}
__device__ __forceinline__ unsigned ordenc(float f) {
    unsigned u = __float_as_uint(f);
    return (u & 0x80000000u) ? ~u : (u | 0x80000000u);
}
__device__ __forceinline__ float orddec(unsigned o) {
    unsigned u = (o & 0x80000000u) ? (o & 0x7FFFFFFFu) : ~o;
    return __uint_as_float(u);
}

// ---------------- c_sq[k] = sum_d c[k][d]^2 (fp32) ----------------
__global__ __launch_bounds__(256) void csq_kernel(const float* __restrict__ cent,
                                                  float* __restrict__ csq) {
    const int wid  = threadIdx.x >> 6;
    const int lane = threadIdx.x & 63;
    const int k = (blockIdx.x << 2) + wid;
    const float* row = cent + (size_t)k * DD;
    float s = 0.f;
#pragma unroll
    for (int d = 0; d < DD; d += 64) {
        float v = row[d + lane];
        s = fmaf(v, v, s);
    }
#pragma unroll
    for (int off = 32; off > 0; off >>= 1) s += __shfl_xor(s, off, 64);
    if (lane == 0) csq[k] = s;
}

// ---------------- exact fp32 rescue for one (row, col) ----------------
__device__ __noinline__ void rescue(const float* __restrict__ x,
                                    const float* __restrict__ cent,
                                    const float* __restrict__ csq,
                                    unsigned long long* __restrict__ keyr,
                                    int r, int k) {
    const float4* xr = (const float4*)(x + (size_t)r * DD);
    const float4* ck = (const float4*)(cent + (size_t)k * DD);
    float s0 = 0.f, s1 = 0.f, s2 = 0.f, s3 = 0.f;
    for (int d = 0; d < DD / 4; ++d) {
        float4 a = xr[d];
        float4 b = ck[d];
        s0 = fmaf(a.x, b.x, s0);
        s1 = fmaf(a.y, b.y, s1);
        s2 = fmaf(a.z, b.z, s2);
        s3 = fmaf(a.w, b.w, s3);
    }
    float dist = fmaf(-2.f, (s0 + s1) + (s2 + s3), csq[k]);
    unsigned long long key = ((unsigned long long)ordenc(dist) << 32) | (unsigned)k;
    atomicMin(keyr, key);
}

// ---------------- bf16 MFMA GEMM, 128x128 tile, BK=64 ----------------
// PASS 1: per-row min of approx dist -> atomicMin(rowmin, ordered-u32)
// PASS 2: elements with dist <= rowmin+DELTA -> exact fp32 rescue -> keys
template <int PASS>
__global__ __launch_bounds__(256) void gemm_pass(
    const float* __restrict__ x, const float* __restrict__ cent,
    const float* __restrict__ csq, unsigned* __restrict__ rowmin,
    unsigned long long* __restrict__ keys)
{
    __shared__ unsigned short Ab[128 * 64];   // 16KB, bf16, 128B rows, XOR-swizzled
    __shared__ unsigned short Bb[128 * 64];   // 16KB

    const int tid = threadIdx.x;
    const int l   = tid & 63;
    const int w   = tid >> 6;            // wave 0..3
    const int wr  = w >> 1, wc = w & 1;  // 2x2 wave grid (64x64 out each)
    const int mblk  = blockIdx.x >> 2;
    const int chunk = blockIdx.x & 3;
    const int m0    = mblk * 128;
    const int nbase = chunk * 1024;      // this block covers 1024 of 4096 cols

    // --- staging roles: waves 0,1 stage A (x rows), waves 2,3 stage B (centroid rows) ---
    const bool isB  = (w >= 2);
    const int sHalf = (w & 1);           // which 64-row half of the tile
    const int sR    = (l >> 3);          // row-in-group 0..7  (== row&7)
    const int sK    = (l & 7);           // 16B bf16 granule 0..7 within 128B row
    const int sSwz  = ((sK ^ sR) << 4);  // XOR swizzle, per-lane constant
    unsigned short* sDst = isB ? Bb : Ab;

    // --- fragment read addressing ---
    const int hi = l >> 4;               // 0..3
    const int ln = l & 15;
    const char* Abase = (const char*)Ab + (wr * 64 + ln) * 128;
    const char* Bbase = (const char*)Bb + (wc * 64 + ln) * 128;
    const int kl0 = (((0 + hi) ^ (l & 7)) << 4);   // kk=0 swizzled k-offset
    const int kl1 = (((4 + hi) ^ (l & 7)) << 4);   // kk=1

    float rm[4][4];
    float thr[4][4];
    if (PASS == 1) {
#pragma unroll
        for (int fr = 0; fr < 4; ++fr)
#pragma unroll
            for (int j = 0; j < 4; ++j) rm[fr][j] = INFINITY;
    } else {
#pragma unroll
        for (int fr = 0; fr < 4; ++fr)
#pragma unroll
            for (int j = 0; j < 4; ++j)
                thr[fr][j] = orddec(rowmin[m0 + wr * 64 + fr * 16 + hi * 4 + j]) + DELTA;
    }

#pragma unroll 1
    for (int nt = 0; nt < 8; ++nt) {
        const int n0 = nbase + nt * 128;
        const float* gs = isB
            ? (cent + (size_t)(n0 + sHalf * 64 + sR) * DD + sK * 8)
            : (x    + (size_t)(m0 + sHalf * 64 + sR) * DD + sK * 8);

        f32x4 acc[4][4];
#pragma unroll
        for (int fr = 0; fr < 4; ++fr)
#pragma unroll
            for (int fc = 0; fc < 4; ++fc) {
                f32x4 z = {0.f, 0.f, 0.f, 0.f};
                acc[fr][fc] = z;
            }

#pragma unroll 1
        for (int k0 = 0; k0 < DD; k0 += 64) {
            // ---- stage 128x64 fp32 -> bf16 LDS tile (this wave's operand) ----
#pragma unroll
            for (int rg = 0; rg < 8; ++rg) {
                const float* p = gs + (size_t)rg * 8 * DD + k0;
                float4 f0 = *(const float4*)(p);
                float4 f1 = *(const float4*)(p + 4);
                unsigned q0 = (unsigned)f2bf(f0.x) | ((unsigned)f2bf(f0.y) << 16);
                unsigned q1 = (unsigned)f2bf(f0.z) | ((unsigned)f2bf(f0.w) << 16);
                unsigned q2 = (unsigned)f2bf(f1.x) | ((unsigned)f2bf(f1.y) << 16);
                unsigned q3 = (unsigned)f2bf(f1.z) | ((unsigned)f2bf(f1.w) << 16);
                uint4 v = make_uint4(q0, q1, q2, q3);
                const int row = sHalf * 64 + rg * 8 + sR;
                *(uint4*)((char*)sDst + row * 128 + sSwz) = v;
            }
            __syncthreads();

            // ---- 2 x (8 frag reads + 16 MFMA) ----
#pragma unroll
            for (int kk = 0; kk < 2; ++kk) {
                const int kl = (kk == 0) ? kl0 : kl1;
                short8 a0 = *(const short8*)(Abase + 0 * 2048 + kl);
                short8 a1 = *(const short8*)(Abase + 1 * 2048 + kl);
                short8 a2 = *(const short8*)(Abase + 2 * 2048 + kl);
                short8 a3 = *(const short8*)(Abase + 3 * 2048 + kl);
                short8 b0 = *(const short8*)(Bbase + 0 * 2048 + kl);
                short8 b1 = *(const short8*)(Bbase + 1 * 2048 + kl);
                short8 b2 = *(const short8*)(Bbase + 2 * 2048 + kl);
                short8 b3 = *(const short8*)(Bbase + 3 * 2048 + kl);
                short8 av[4] = {a0, a1, a2, a3};
                short8 bv[4] = {b0, b1, b2, b3};
#pragma unroll
                for (int fr = 0; fr < 4; ++fr)
#pragma unroll
                    for (int fc = 0; fc < 4; ++fc)
                        acc[fr][fc] = __builtin_amdgcn_mfma_f32_16x16x32_bf16(
                            av[fr], bv[fc], acc[fr][fc], 0, 0, 0);
            }
            __syncthreads();
        }

        // ---- epilogue: dist = csq[col] - 2*acc ----
#pragma unroll
        for (int fc = 0; fc < 4; ++fc) {
            const int col = n0 + wc * 64 + fc * 16 + ln;
            const float q = csq[col];
#pragma unroll
            for (int fr = 0; fr < 4; ++fr)
#pragma unroll
                for (int j = 0; j < 4; ++j) {
                    const float dist = fmaf(-2.f, acc[fr][fc][j], q);
                    if (PASS == 1) {
                        rm[fr][j] = fminf(rm[fr][j], dist);
                    } else {
                        if (dist <= thr[fr][j])
                            rescue(x, cent, csq,
                                   keys + (m0 + wr * 64 + fr * 16 + hi * 4 + j), 
                                   m0 + wr * 64 + fr * 16 + hi * 4 + j, col);
                    }
                }
        }
    }

    if (PASS == 1) {
        // reduce min across the 16 ln-lanes (same hi), then one atomic per row
#pragma unroll
        for (int off = 1; off < 16; off <<= 1)
#pragma unroll
            for (int fr = 0; fr < 4; ++fr)
#pragma unroll
                for (int j = 0; j < 4; ++j)
                    rm[fr][j] = fminf(rm[fr][j], __shfl_xor(rm[fr][j], off, 64));
        if (ln == 0) {
#pragma unroll
            for (int fr = 0; fr < 4; ++fr)
#pragma unroll
                for (int j = 0; j < 4; ++j)
                    atomicMin(&rowmin[m0 + wr * 64 + fr * 16 + hi * 4 + j],
                              ordenc(rm[fr][j]));
        }
    }
}

__global__ __launch_bounds__(256) void finalize_kernel(
        const unsigned long long* __restrict__ keys, int* __restrict__ out) {
    const int i = blockIdx.x * 256 + threadIdx.x;
    out[i] = (int)(keys[i] & 0xFFFFFFFFull);
}

// ---------------- fallback: round-1 fp32 kernel (proven) ----------------
__global__ __launch_bounds__(256) void argmin_fp32_kernel(
        const float* __restrict__ x, const float* __restrict__ cent,
        const float* __restrict__ csq, int* __restrict__ out) {
    __shared__ float xs[16][68];
    __shared__ float cs[16][132];
    const int tid = threadIdx.x;
    const int tx = tid & 15;
    const int ty = tid >> 4;
    const int m0 = blockIdx.x * 64;
    const int srow = tid >> 2;
    const int scol = (tid & 3) << 2;
    const float* xg  = x + (size_t)(m0 + srow) * DD + scol;
    const float* cgA = cent + (size_t)srow * DD + scol;
    const float* cgB = cent + (size_t)(srow + 64) * DD + scol;
    float best[4];
    int bidx[4];
#pragma unroll
    for (int i = 0; i < 4; ++i) { best[i] = INFINITY; bidx[i] = 0; }
    for (int n0 = 0; n0 < KC; n0 += 128) {
        float acc[4][2][4];
#pragma unroll
        for (int i = 0; i < 4; ++i)
#pragma unroll
            for (int h = 0; h < 2; ++h)
#pragma unroll
                for (int j = 0; j < 4; ++j) acc[i][h][j] = 0.f;
        const size_t nOff = (size_t)n0 * DD;
        float4 rx = *(const float4*)(xg);
        float4 rc0 = *(const float4*)(cgA + nOff);
        float4 rc1 = *(const float4*)(cgB + nOff);
        for (int k0 = 0; k0 < DD; k0 += 16) {
            __syncthreads();
            const float* p = (const float*)&rx;
            xs[scol + 0][srow] = p[0]; xs[scol + 1][srow] = p[1];
            xs[scol + 2][srow] = p[2]; xs[scol + 3][srow] = p[3];
            const float* q0 = (const float*)&rc0;
            cs[scol + 0][srow] = q0[0]; cs[scol + 1][srow] = q0[1];
            cs[scol + 2][srow] = q0[2]; cs[scol + 3][srow] = q0[3];
            const float* q1 = (const float*)&rc1;
            cs[scol + 0][srow + 64] = q1[0]; cs[scol + 1][srow + 64] = q1[1];
            cs[scol + 2][srow + 64] = q1[2]; cs[scol + 3][srow + 64] = q1[3];
            __syncthreads();
            if (k0 + 16 < DD) {
                rx  = *(const float4*)(xg + k0 + 16);
                rc0 = *(const float4*)(cgA + nOff + k0 + 16);
                rc1 = *(const float4*)(cgB + nOff + k0 + 16);
            }
#pragma unroll
            for (int dd = 0; dd < 16; ++dd) {
                float4 av  = *(const float4*)&xs[dd][ty << 2];
                float4 bv0 = *(const float4*)&cs[dd][tx << 2];
                float4 bv1 = *(const float4*)&cs[dd][64 + (tx << 2)];
                const float* a  = (const float*)&av;
                const float* b0 = (const float*)&bv0;
                const float* b1 = (const float*)&bv1;
#pragma unroll
                for (int i = 0; i < 4; ++i)
#pragma unroll
                    for (int j = 0; j < 4; ++j) {
                        acc[i][0][j] = fmaf(a[i], b0[j], acc[i][0][j]);
                        acc[i][1][j] = fmaf(a[i], b1[j], acc[i][1][j]);
                    }
            }
        }
        float4 qv0 = *(const float4*)(csq + n0 + (tx << 2));
        float4 qv1 = *(const float4*)(csq + n0 + 64 + (tx << 2));
        const float* q0 = (const float*)&qv0;
        const float* q1 = (const float*)&qv1;
#pragma unroll
        for (int i = 0; i < 4; ++i)
#pragma unroll
            for (int h = 0; h < 2; ++h)
#pragma unroll
                for (int j = 0; j < 4; ++j) {
                    float qq = (h == 0) ? q0[j] : q1[j];
                    float dist = fmaf(-2.f, acc[i][h][j], qq);
                    int kk = n0 + h * 64 + (tx << 2) + j;
                    if (dist < best[i] || (dist == best[i] && kk < bidx[i])) {
                        best[i] = dist; bidx[i] = kk;
                    }
                }
    }
#pragma unroll
    for (int off = 1; off < 16; off <<= 1)
#pragma unroll
        for (int i = 0; i < 4; ++i) {
            float ov = __shfl_xor(best[i], off, 64);
            int oi = __shfl_xor(bidx[i], off, 64);
            if (ov < best[i] || (ov == best[i] && oi < bidx[i])) {
                best[i] = ov; bidx[i] = oi;
            }
        }
    if (tx == 0)
#pragma unroll
        for (int i = 0; i < 4; ++i) out[m0 + (ty << 2) + i] = bidx[i];
}

extern "C" void kernel_launch(void* const* d_in, const int* in_sizes, int n_in,
                              void* d_out, int out_size, void* d_ws, size_t ws_size,
                              hipStream_t stream) {
    const float* x    = (const float*)d_in[0];
    const float* cent = (const float*)d_in[1];
    int* out = (int*)d_out;

    const size_t rowmin_bytes = (size_t)NB * 4;   // 128KB
    const size_t keys_bytes   = (size_t)NB * 8;   // 256KB
    const size_t csq_bytes    = (size_t)KC * 4;   // 16KB

    if (ws_size >= rowmin_bytes + keys_bytes + csq_bytes) {
        unsigned* rowmin = (unsigned*)d_ws;
        unsigned long long* keys = (unsigned long long*)((char*)d_ws + rowmin_bytes);
        float* csq = (float*)((char*)d_ws + rowmin_bytes + keys_bytes);
        hipMemsetAsync(rowmin, 0xFF, rowmin_bytes, stream);
        hipMemsetAsync(keys, 0xFF, keys_bytes, stream);
        csq_kernel<<<KC / 4, 256, 0, stream>>>(cent, csq);
        gemm_pass<1><<<(NB / 128) * 4, 256, 0, stream>>>(x, cent, csq, rowmin, nullptr);
        gemm_pass<2><<<(NB / 128) * 4, 256, 0, stream>>>(x, cent, csq, rowmin, keys);
        finalize_kernel<<<NB / 256, 256, 0, stream>>>(keys, out);
    } else {
        float* csq = (float*)d_ws;
        csq_kernel<<<KC / 4, 256, 0, stream>>>(cent, csq);
        argmin_fp32_kernel<<<NB / 64, 256, 0, stream>>>(x, cent, csq, out);
    }
}

// Round 3
// 1782.530 us; speedup vs baseline: 1.0673x; 1.0673x over previous
//
#include <hip/hip_runtime.h>
#include <math.h>

#define NB 32768
#define KC 4096
#define DD 512
#define DELTA 4.0f

typedef __attribute__((ext_vector_type(8))) short short8;
typedef __attribute__((ext_vector_type(4))) float facc4;

#define AS1 __attribute__((address_space(1)))
#define AS3 __attribute__((address_space(3)))

__device__ __forceinline__ void gll16(const void* g, void* lds) {
    // async global->LDS, 16B per lane; LDS dest = wave-uniform base + lane*16
    __builtin_amdgcn_global_load_lds((const AS1 unsigned*)g, (AS3 unsigned*)lds,
                                     16, 0, 0);
}

__device__ __forceinline__ unsigned short f2bf(float f) {
    unsigned u = __float_as_uint(f);
    u += 0x7FFFu + ((u >> 16) & 1u);     // RNE
    return (unsigned short)(u >> 16);
}
__device__ __forceinline__ unsigned ordenc(float f) {
    unsigned u = __float_as_uint(f);
    return (u & 0x80000000u) ? ~u : (u | 0x80000000u);
}
__device__ __forceinline__ float orddec(unsigned o) {
    unsigned u = (o & 0x80000000u) ? (o & 0x7FFFFFFFu) : ~o;
    return __uint_as_float(u);
}

// ---------------- fp32 -> bf16 bulk convert (8 elems/thread) ----------------
__global__ __launch_bounds__(256) void cvt_bf16_kernel(const float* __restrict__ in,
                                                       unsigned short* __restrict__ out) {
    const int i = blockIdx.x * 256 + threadIdx.x;
    const float4* p = (const float4*)in + (size_t)i * 2;
    float4 a = p[0], b = p[1];
    unsigned q0 = (unsigned)f2bf(a.x) | ((unsigned)f2bf(a.y) << 16);
    unsigned q1 = (unsigned)f2bf(a.z) | ((unsigned)f2bf(a.w) << 16);
    unsigned q2 = (unsigned)f2bf(b.x) | ((unsigned)f2bf(b.y) << 16);
    unsigned q3 = (unsigned)f2bf(b.z) | ((unsigned)f2bf(b.w) << 16);
    ((uint4*)out)[i] = make_uint4(q0, q1, q2, q3);
}

// ---------------- c_sq[k] = sum_d c[k][d]^2 (fp32) ----------------
__global__ __launch_bounds__(256) void csq_kernel(const float* __restrict__ cent,
                                                  float* __restrict__ csq) {
    const int wid  = threadIdx.x >> 6;
    const int lane = threadIdx.x & 63;
    const int k = (blockIdx.x << 2) + wid;
    const float* row = cent + (size_t)k * DD;
    float s = 0.f;
#pragma unroll
    for (int d = 0; d < DD; d += 64) {
        float v = row[d + lane];
        s = fmaf(v, v, s);
    }
#pragma unroll
    for (int off = 32; off > 0; off >>= 1) s += __shfl_xor(s, off, 64);
    if (lane == 0) csq[k] = s;
}

// ---------------- exact fp32 rescue for one (row, col) ----------------
__device__ __noinline__ void rescue(const float* __restrict__ x,
                                    const float* __restrict__ cent,
                                    const float* __restrict__ csq,
                                    unsigned long long* __restrict__ keyr,
                                    int r, int k) {
    const float4* xr = (const float4*)(x + (size_t)r * DD);
    const float4* ck = (const float4*)(cent + (size_t)k * DD);
    float s0 = 0.f, s1 = 0.f, s2 = 0.f, s3 = 0.f;
    for (int d = 0; d < DD / 4; ++d) {
        float4 a = xr[d];
        float4 b = ck[d];
        s0 = fmaf(a.x, b.x, s0);
        s1 = fmaf(a.y, b.y, s1);
        s2 = fmaf(a.z, b.z, s2);
        s3 = fmaf(a.w, b.w, s3);
    }
    float dist = fmaf(-2.f, (s0 + s1) + (s2 + s3), csq[k]);
    unsigned long long key = ((unsigned long long)ordenc(dist) << 32) | (unsigned)k;
    atomicMin(keyr, key);
}

// ---------------- m97-style bf16 MFMA GEMM, 128x128 tile, BK=64 ----------------
// grid: (NB/128) * (KC/128); n fastest (L2 panel reuse). 4 waves, 2x2, 4x4 frags.
// Staging: global_load_lds 16B/lane, linear LDS, XOR-swizzle applied on the
// GLOBAL source granule (rule #21); reads use the round-2-validated XOR read.
template <int PASS>
__global__ __launch_bounds__(256) void gemm_fast(
    const unsigned short* __restrict__ xb, const unsigned short* __restrict__ cb,
    const float* __restrict__ x, const float* __restrict__ cent,
    const float* __restrict__ csq, unsigned* __restrict__ rowmin,
    unsigned long long* __restrict__ keys)
{
    __shared__ unsigned short Ab[128 * 64];   // 16KB
    __shared__ unsigned short Bb[128 * 64];   // 16KB

    const int tid = threadIdx.x;
    const int l = tid & 63, w = tid >> 6;
    const int wr = w >> 1, wc = w & 1;
    const int mblk = blockIdx.x >> 5, nblk = blockIdx.x & 31;
    const int m0 = mblk * 128, n0 = nblk * 128;

    // --- staging addressing: lane l covers row (l>>3), granule (l&7) of each 32-row slab
    const int srow = l >> 3;                       // 0..7
    const int sswz = ((l & 7) ^ srow) << 3;        // swizzled granule, in elements
    const unsigned short* ga = xb + (size_t)(m0 + w * 8 + srow) * DD + sswz;
    const unsigned short* gb = cb + (size_t)(n0 + w * 8 + srow) * DD + sswz;

    // --- fragment read addressing (validated round 2) ---
    const int hi = l >> 4, ln = l & 15;
    const char* Ar = (const char*)Ab + (wr * 64 + ln) * 128;
    const char* Br = (const char*)Bb + (wc * 64 + ln) * 128;

    float rm[4][4];
    float thr[4][4];
    if (PASS == 1) {
#pragma unroll
        for (int fr = 0; fr < 4; ++fr)
#pragma unroll
            for (int j = 0; j < 4; ++j) rm[fr][j] = INFINITY;
    } else {
#pragma unroll
        for (int fr = 0; fr < 4; ++fr)
#pragma unroll
            for (int j = 0; j < 4; ++j)
                thr[fr][j] = orddec(rowmin[m0 + wr * 64 + fr * 16 + hi * 4 + j]) + DELTA;
    }

    facc4 acc[4][4];
#pragma unroll
    for (int fr = 0; fr < 4; ++fr)
#pragma unroll
        for (int fc = 0; fc < 4; ++fc) {
            facc4 z = {0.f, 0.f, 0.f, 0.f};
            acc[fr][fc] = z;
        }

#pragma unroll 1
    for (int k0 = 0; k0 < DD; k0 += 64) {
        // ---- stage both 128x64 bf16 tiles: 8 async 4KB issues ----
#pragma unroll
        for (int i = 0; i < 4; ++i) {
            gll16(ga + (size_t)i * 32 * DD + k0, (void*)(Ab + i * 2048 + w * 512));
            gll16(gb + (size_t)i * 32 * DD + k0, (void*)(Bb + i * 2048 + w * 512));
        }
        __syncthreads();   // drains vmcnt (global_load_lds) + lgkm

        // ---- 2 x (8 ds_read_b128 + 16 MFMA) ----
#pragma unroll
        for (int kk = 0; kk < 2; ++kk) {
            const int kl = (((kk * 4 + hi) ^ (l & 7)) << 4);
            short8 av[4], bv[4];
#pragma unroll
            for (int fr = 0; fr < 4; ++fr) av[fr] = *(const short8*)(Ar + fr * 2048 + kl);
#pragma unroll
            for (int fc = 0; fc < 4; ++fc) bv[fc] = *(const short8*)(Br + fc * 2048 + kl);
#pragma unroll
            for (int fr = 0; fr < 4; ++fr)
#pragma unroll
                for (int fc = 0; fc < 4; ++fc)
                    acc[fr][fc] = __builtin_amdgcn_mfma_f32_16x16x32_bf16(
                        av[fr], bv[fc], acc[fr][fc], 0, 0, 0);
        }
        __syncthreads();   // protect LDS before next stage
    }

    // ---- epilogue: dist = csq[col] - 2*acc ----
#pragma unroll
    for (int fc = 0; fc < 4; ++fc) {
        const int col = n0 + wc * 64 + fc * 16 + ln;
        const float q = csq[col];
#pragma unroll
        for (int fr = 0; fr < 4; ++fr)
#pragma unroll
            for (int j = 0; j < 4; ++j) {
                const float dist = fmaf(-2.f, acc[fr][fc][j], q);
                if (PASS == 1) {
                    rm[fr][j] = fminf(rm[fr][j], dist);
                } else {
                    if (dist <= thr[fr][j]) {
                        const int row = m0 + wr * 64 + fr * 16 + hi * 4 + j;
                        rescue(x, cent, csq, keys + row, row, col);
                    }
                }
            }
    }

    if (PASS == 1) {
#pragma unroll
        for (int off = 1; off < 16; off <<= 1)
#pragma unroll
            for (int fr = 0; fr < 4; ++fr)
#pragma unroll
                for (int j = 0; j < 4; ++j)
                    rm[fr][j] = fminf(rm[fr][j], __shfl_xor(rm[fr][j], off, 64));
        if (ln == 0) {
#pragma unroll
            for (int fr = 0; fr < 4; ++fr)
#pragma unroll
                for (int j = 0; j < 4; ++j)
                    atomicMin(&rowmin[m0 + wr * 64 + fr * 16 + hi * 4 + j],
                              ordenc(rm[fr][j]));
        }
    }
}

__global__ __launch_bounds__(256) void finalize_kernel(
        const unsigned long long* __restrict__ keys, int* __restrict__ out) {
    const int i = blockIdx.x * 256 + threadIdx.x;
    out[i] = (int)(keys[i] & 0xFFFFFFFFull);
}

// ---------------- fallback: round-1 fp32 kernel (proven, 1876us) ----------------
__global__ __launch_bounds__(256) void argmin_fp32_kernel(
        const float* __restrict__ x, const float* __restrict__ cent,
        const float* __restrict__ csq, int* __restrict__ out) {
    __shared__ float xs[16][68];
    __shared__ float cs[16][132];
    const int tid = threadIdx.x;
    const int tx = tid & 15;
    const int ty = tid >> 4;
    const int m0 = blockIdx.x * 64;
    const int srow = tid >> 2;
    const int scol = (tid & 3) << 2;
    const float* xg  = x + (size_t)(m0 + srow) * DD + scol;
    const float* cgA = cent + (size_t)srow * DD + scol;
    const float* cgB = cent + (size_t)(srow + 64) * DD + scol;
    float best[4];
    int bidx[4];
#pragma unroll
    for (int i = 0; i < 4; ++i) { best[i] = INFINITY; bidx[i] = 0; }
    for (int n0 = 0; n0 < KC; n0 += 128) {
        float acc[4][2][4];
#pragma unroll
        for (int i = 0; i < 4; ++i)
#pragma unroll
            for (int h = 0; h < 2; ++h)
#pragma unroll
                for (int j = 0; j < 4; ++j) acc[i][h][j] = 0.f;
        const size_t nOff = (size_t)n0 * DD;
        float4 rx = *(const float4*)(xg);
        float4 rc0 = *(const float4*)(cgA + nOff);
        float4 rc1 = *(const float4*)(cgB + nOff);
        for (int k0 = 0; k0 < DD; k0 += 16) {
            __syncthreads();
            const float* p = (const float*)&rx;
            xs[scol + 0][srow] = p[0]; xs[scol + 1][srow] = p[1];
            xs[scol + 2][srow] = p[2]; xs[scol + 3][srow] = p[3];
            const float* q0 = (const float*)&rc0;
            cs[scol + 0][srow] = q0[0]; cs[scol + 1][srow] = q0[1];
            cs[scol + 2][srow] = q0[2]; cs[scol + 3][srow] = q0[3];
            const float* q1 = (const float*)&rc1;
            cs[scol + 0][srow + 64] = q1[0]; cs[scol + 1][srow + 64] = q1[1];
            cs[scol + 2][srow + 64] = q1[2]; cs[scol + 3][srow + 64] = q1[3];
            __syncthreads();
            if (k0 + 16 < DD) {
                rx  = *(const float4*)(xg + k0 + 16);
                rc0 = *(const float4*)(cgA + nOff + k0 + 16);
                rc1 = *(const float4*)(cgB + nOff + k0 + 16);
            }
#pragma unroll
            for (int dd = 0; dd < 16; ++dd) {
                float4 av  = *(const float4*)&xs[dd][ty << 2];
                float4 bv0 = *(const float4*)&cs[dd][tx << 2];
                float4 bv1 = *(const float4*)&cs[dd][64 + (tx << 2)];
                const float* a  = (const float*)&av;
                const float* b0 = (const float*)&bv0;
                const float* b1 = (const float*)&bv1;
#pragma unroll
                for (int i = 0; i < 4; ++i)
#pragma unroll
                    for (int j = 0; j < 4; ++j) {
                        acc[i][0][j] = fmaf(a[i], b0[j], acc[i][0][j]);
                        acc[i][1][j] = fmaf(a[i], b1[j], acc[i][1][j]);
                    }
            }
        }
        float4 qv0 = *(const float4*)(csq + n0 + (tx << 2));
        float4 qv1 = *(const float4*)(csq + n0 + 64 + (tx << 2));
        const float* q0 = (const float*)&qv0;
        const float* q1 = (const float*)&qv1;
#pragma unroll
        for (int i = 0; i < 4; ++i)
#pragma unroll
            for (int h = 0; h < 2; ++h)
#pragma unroll
                for (int j = 0; j < 4; ++j) {
                    float qq = (h == 0) ? q0[j] : q1[j];
                    float dist = fmaf(-2.f, acc[i][h][j], qq);
                    int kk = n0 + h * 64 + (tx << 2) + j;
                    if (dist < best[i] || (dist == best[i] && kk < bidx[i])) {
                        best[i] = dist; bidx[i] = kk;
                    }
                }
    }
#pragma unroll
    for (int off = 1; off < 16; off <<= 1)
#pragma unroll
        for (int i = 0; i < 4; ++i) {
            float ov = __shfl_xor(best[i], off, 64);
            int oi = __shfl_xor(bidx[i], off, 64);
            if (ov < best[i] || (ov == best[i] && oi < bidx[i])) {
                best[i] = ov; bidx[i] = oi;
            }
        }
    if (tx == 0)
#pragma unroll
        for (int i = 0; i < 4; ++i) out[m0 + (ty << 2) + i] = bidx[i];
}

extern "C" void kernel_launch(void* const* d_in, const int* in_sizes, int n_in,
                              void* d_out, int out_size, void* d_ws, size_t ws_size,
                              hipStream_t stream) {
    const float* x    = (const float*)d_in[0];
    const float* cent = (const float*)d_in[1];
    int* out = (int*)d_out;

    const size_t xb_bytes     = (size_t)NB * DD * 2;   // 32MB
    const size_t cb_bytes     = (size_t)KC * DD * 2;   // 4MB
    const size_t rowmin_bytes = (size_t)NB * 4;        // 128KB
    const size_t keys_bytes   = (size_t)NB * 8;        // 256KB
    const size_t csq_bytes    = (size_t)KC * 4;        // 16KB
    const size_t need = xb_bytes + cb_bytes + rowmin_bytes + keys_bytes + csq_bytes;

    if (ws_size >= need) {
        unsigned short* xb = (unsigned short*)d_ws;
        unsigned short* cb = (unsigned short*)((char*)d_ws + xb_bytes);
        unsigned* rowmin = (unsigned*)((char*)d_ws + xb_bytes + cb_bytes);
        unsigned long long* keys =
            (unsigned long long*)((char*)d_ws + xb_bytes + cb_bytes + rowmin_bytes);
        float* csq = (float*)((char*)d_ws + xb_bytes + cb_bytes + rowmin_bytes + keys_bytes);

        hipMemsetAsync(rowmin, 0xFF, rowmin_bytes, stream);
        hipMemsetAsync(keys, 0xFF, keys_bytes, stream);
        cvt_bf16_kernel<<<NB * DD / 8 / 256, 256, 0, stream>>>(x, xb);
        cvt_bf16_kernel<<<KC * DD / 8 / 256, 256, 0, stream>>>(cent, cb);
        csq_kernel<<<KC / 4, 256, 0, stream>>>(cent, csq);
        gemm_fast<1><<<(NB / 128) * (KC / 128), 256, 0, stream>>>(
            xb, cb, x, cent, csq, rowmin, nullptr);
        gemm_fast<2><<<(NB / 128) * (KC / 128), 256, 0, stream>>>(
            xb, cb, x, cent, csq, rowmin, keys);
        finalize_kernel<<<NB / 256, 256, 0, stream>>>(keys, out);
    } else {
        float* csq = (float*)d_ws;
        csq_kernel<<<KC / 4, 256, 0, stream>>>(cent, csq);
        argmin_fp32_kernel<<<NB / 64, 256, 0, stream>>>(x, cent, csq, out);
    }
}

// Round 4
// 1154.162 us; speedup vs baseline: 1.6484x; 1.5444x over previous
//
#include <hip/hip_runtime.h>
#include <math.h>

#define NB 32768
#define KC 4096
#define DD 512
#define DELTA 4.0f

typedef __attribute__((ext_vector_type(8))) short short8;
typedef __attribute__((ext_vector_type(4))) float facc4;

#define AS1 __attribute__((address_space(1)))
#define AS3 __attribute__((address_space(3)))

__device__ __forceinline__ void gll16(const void* g, void* lds) {
    __builtin_amdgcn_global_load_lds((const AS1 unsigned*)g, (AS3 unsigned*)lds,
                                     16, 0, 0);
}

__device__ __forceinline__ unsigned short f2bf(float f) {
    unsigned u = __float_as_uint(f);
    u += 0x7FFFu + ((u >> 16) & 1u);     // RNE
    return (unsigned short)(u >> 16);
}
__device__ __forceinline__ unsigned ordenc(float f) {
    unsigned u = __float_as_uint(f);
    return (u & 0x80000000u) ? ~u : (u | 0x80000000u);
}
__device__ __forceinline__ float orddec(unsigned o) {
    unsigned u = (o & 0x80000000u) ? (o & 0x7FFFFFFFu) : ~o;
    return __uint_as_float(u);
}

// ---- fp32 -> bf16 convert + tile to [blk][kstep][128 r][64 d] (LDS image) ----
__global__ __launch_bounds__(256) void tile_bf16_kernel(const float* __restrict__ in,
                                                        unsigned short* __restrict__ out) {
    const size_t t = (size_t)blockIdx.x * 256 + threadIdx.x;
    const int row = (int)(t >> 6);
    const int d0  = (int)(t & 63) << 3;
    const int blk = row >> 7, r = row & 127;
    const int ks  = d0 >> 6,  dw = d0 & 63;
    const float4* p = (const float4*)(in + (size_t)row * DD + d0);
    float4 a = p[0], b = p[1];
    unsigned q0 = (unsigned)f2bf(a.x) | ((unsigned)f2bf(a.y) << 16);
    unsigned q1 = (unsigned)f2bf(a.z) | ((unsigned)f2bf(a.w) << 16);
    unsigned q2 = (unsigned)f2bf(b.x) | ((unsigned)f2bf(b.y) << 16);
    unsigned q3 = (unsigned)f2bf(b.z) | ((unsigned)f2bf(b.w) << 16);
    const size_t o = (((size_t)blk * 8 + ks) * 128 + r) * 64 + dw;
    *(uint4*)(out + o) = make_uint4(q0, q1, q2, q3);
}

// ---------------- c_sq[k] = sum_d c[k][d]^2 (fp32) ----------------
__global__ __launch_bounds__(256) void csq_kernel(const float* __restrict__ cent,
                                                  float* __restrict__ csq) {
    const int wid  = threadIdx.x >> 6;
    const int lane = threadIdx.x & 63;
    const int k = (blockIdx.x << 2) + wid;
    const float* row = cent + (size_t)k * DD;
    float s = 0.f;
#pragma unroll
    for (int d = 0; d < DD; d += 64) {
        float v = row[d + lane];
        s = fmaf(v, v, s);
    }
#pragma unroll
    for (int off = 32; off > 0; off >>= 1) s += __shfl_xor(s, off, 64);
    if (lane == 0) csq[k] = s;
}

// ---------------- exact fp32 rescue for one (row, col) ----------------
__device__ __noinline__ void rescue(const float* __restrict__ x,
                                    const float* __restrict__ cent,
                                    const float* __restrict__ csq,
                                    unsigned long long* __restrict__ keyr,
                                    int r, int k) {
    const float4* xr = (const float4*)(x + (size_t)r * DD);
    const float4* ck = (const float4*)(cent + (size_t)k * DD);
    float s0 = 0.f, s1 = 0.f, s2 = 0.f, s3 = 0.f;
    for (int d = 0; d < DD / 4; ++d) {
        float4 a = xr[d];
        float4 b = ck[d];
        s0 = fmaf(a.x, b.x, s0);
        s1 = fmaf(a.y, b.y, s1);
        s2 = fmaf(a.z, b.z, s2);
        s3 = fmaf(a.w, b.w, s3);
    }
    float dist = fmaf(-2.f, (s0 + s1) + (s2 + s3), csq[k]);
    unsigned long long key = ((unsigned long long)ordenc(dist) << 32) | (unsigned)k;
    atomicMin(keyr, key);
}

// ------- m97-exact bf16 MFMA GEMM on pre-tiled operands, 2-phase dbuf -------
// xbT/cbT: [blk][kstep][128][64] bf16 — staging is lane-linear contiguous 1KB
// per gll16, LDS fully linear (no swizzle; T2 is null on 2-phase structures).
template <int PASS>
__global__ __launch_bounds__(256) void gemm_fast2(
    const unsigned short* __restrict__ xbT, const unsigned short* __restrict__ cbT,
    const float* __restrict__ x, const float* __restrict__ cent,
    const float* __restrict__ csq, unsigned* __restrict__ rowmin,
    unsigned long long* __restrict__ keys)
{
    __shared__ unsigned short Ab[2][8192];   // 2 x 16KB
    __shared__ unsigned short Bb[2][8192];

    const int tid = threadIdx.x;
    const int l = tid & 63, w = tid >> 6;
    const int wr = w >> 1, wc = w & 1;

    // XCD-aware chunked remap: each XCD owns 1024 consecutive logical tiles
    const int bid = blockIdx.x;
    const int swz = (bid & 7) * 1024 + (bid >> 3);
    const int mblk = swz >> 5, nblk = swz & 31;
    const int m0 = mblk * 128, n0 = nblk * 128;

    // staging: wave w copies quarter-tile (4KB) as 4 contiguous 1KB gll16
    const unsigned short* ga = xbT + (size_t)mblk * 8 * 8192 + w * 2048 + l * 8;
    const unsigned short* gb = cbT + (size_t)nblk * 8 * 8192 + w * 2048 + l * 8;

#define STAGE(buf, ks)                                                        \
    do {                                                                      \
        const unsigned short* sa_ = ga + (size_t)(ks) * 8192;                 \
        const unsigned short* sb_ = gb + (size_t)(ks) * 8192;                 \
        _Pragma("unroll")                                                     \
        for (int i_ = 0; i_ < 4; ++i_) {                                      \
            gll16(sa_ + i_ * 512, &Ab[buf][w * 2048 + i_ * 512]);             \
            gll16(sb_ + i_ * 512, &Bb[buf][w * 2048 + i_ * 512]);             \
        }                                                                     \
    } while (0)

    // fragment read addressing (validated rounds 2-3), linear LDS [row][64]
    const int hi = l >> 4, ln = l & 15;

    float rm[4][4];
    float thr[4][4];
    if (PASS == 1) {
#pragma unroll
        for (int fr = 0; fr < 4; ++fr)
#pragma unroll
            for (int j = 0; j < 4; ++j) rm[fr][j] = INFINITY;
    } else {
#pragma unroll
        for (int fr = 0; fr < 4; ++fr)
#pragma unroll
            for (int j = 0; j < 4; ++j)
                thr[fr][j] = orddec(rowmin[m0 + wr * 64 + fr * 16 + hi * 4 + j]) + DELTA;
    }

    facc4 acc[4][4];
#pragma unroll
    for (int fr = 0; fr < 4; ++fr)
#pragma unroll
        for (int fc = 0; fc < 4; ++fc) {
            facc4 z = {0.f, 0.f, 0.f, 0.f};
            acc[fr][fc] = z;
        }

#define COMPUTE(buf)                                                          \
    do {                                                                      \
        _Pragma("unroll")                                                     \
        for (int kk = 0; kk < 2; ++kk) {                                      \
            const int ko_ = (kk * 4 + hi) * 8;                                \
            short8 av[4], bv[4];                                              \
            _Pragma("unroll")                                                 \
            for (int fr = 0; fr < 4; ++fr)                                    \
                av[fr] = *(const short8*)&Ab[buf][(wr * 64 + fr * 16 + ln) * 64 + ko_]; \
            _Pragma("unroll")                                                 \
            for (int fc = 0; fc < 4; ++fc)                                    \
                bv[fc] = *(const short8*)&Bb[buf][(wc * 64 + fc * 16 + ln) * 64 + ko_]; \
            _Pragma("unroll")                                                 \
            for (int fr = 0; fr < 4; ++fr)                                    \
                _Pragma("unroll")                                             \
                for (int fc = 0; fc < 4; ++fc)                                \
                    acc[fr][fc] = __builtin_amdgcn_mfma_f32_16x16x32_bf16(    \
                        av[fr], bv[fc], acc[fr][fc], 0, 0, 0);                \
        }                                                                     \
    } while (0)

    // 2-phase pipeline: stage(t+1) in flight while compute(t) runs;
    // __syncthreads() drains vmcnt+lgkm once per round.
    STAGE(0, 0);
    __syncthreads();
#pragma unroll
    for (int t = 0; t < 7; ++t) {
        STAGE((t + 1) & 1, t + 1);
        COMPUTE(t & 1);
        __syncthreads();
    }
    COMPUTE(1);

    // ---- epilogue: dist = csq[col] - 2*acc (validated) ----
#pragma unroll
    for (int fc = 0; fc < 4; ++fc) {
        const int col = n0 + wc * 64 + fc * 16 + ln;
        const float q = csq[col];
#pragma unroll
        for (int fr = 0; fr < 4; ++fr)
#pragma unroll
            for (int j = 0; j < 4; ++j) {
                const float dist = fmaf(-2.f, acc[fr][fc][j], q);
                if (PASS == 1) {
                    rm[fr][j] = fminf(rm[fr][j], dist);
                } else {
                    if (dist <= thr[fr][j]) {
                        const int row = m0 + wr * 64 + fr * 16 + hi * 4 + j;
                        rescue(x, cent, csq, keys + row, row, col);
                    }
                }
            }
    }

    if (PASS == 1) {
#pragma unroll
        for (int off = 1; off < 16; off <<= 1)
#pragma unroll
            for (int fr = 0; fr < 4; ++fr)
#pragma unroll
                for (int j = 0; j < 4; ++j)
                    rm[fr][j] = fminf(rm[fr][j], __shfl_xor(rm[fr][j], off, 64));
        if (ln == 0) {
#pragma unroll
            for (int fr = 0; fr < 4; ++fr)
#pragma unroll
                for (int j = 0; j < 4; ++j)
                    atomicMin(&rowmin[m0 + wr * 64 + fr * 16 + hi * 4 + j],
                              ordenc(rm[fr][j]));
        }
    }
#undef STAGE
#undef COMPUTE
}

__global__ __launch_bounds__(256) void finalize_kernel(
        const unsigned long long* __restrict__ keys, int* __restrict__ out) {
    const int i = blockIdx.x * 256 + threadIdx.x;
    out[i] = (int)(keys[i] & 0xFFFFFFFFull);
}

// ---------------- fallback: round-1 fp32 kernel (proven) ----------------
__global__ __launch_bounds__(256) void argmin_fp32_kernel(
        const float* __restrict__ x, const float* __restrict__ cent,
        const float* __restrict__ csq, int* __restrict__ out) {
    __shared__ float xs[16][68];
    __shared__ float cs[16][132];
    const int tid = threadIdx.x;
    const int tx = tid & 15;
    const int ty = tid >> 4;
    const int m0 = blockIdx.x * 64;
    const int srow = tid >> 2;
    const int scol = (tid & 3) << 2;
    const float* xg  = x + (size_t)(m0 + srow) * DD + scol;
    const float* cgA = cent + (size_t)srow * DD + scol;
    const float* cgB = cent + (size_t)(srow + 64) * DD + scol;
    float best[4];
    int bidx[4];
#pragma unroll
    for (int i = 0; i < 4; ++i) { best[i] = INFINITY; bidx[i] = 0; }
    for (int n0 = 0; n0 < KC; n0 += 128) {
        float acc[4][2][4];
#pragma unroll
        for (int i = 0; i < 4; ++i)
#pragma unroll
            for (int h = 0; h < 2; ++h)
#pragma unroll
                for (int j = 0; j < 4; ++j) acc[i][h][j] = 0.f;
        const size_t nOff = (size_t)n0 * DD;
        float4 rx = *(const float4*)(xg);
        float4 rc0 = *(const float4*)(cgA + nOff);
        float4 rc1 = *(const float4*)(cgB + nOff);
        for (int k0 = 0; k0 < DD; k0 += 16) {
            __syncthreads();
            const float* p = (const float*)&rx;
            xs[scol + 0][srow] = p[0]; xs[scol + 1][srow] = p[1];
            xs[scol + 2][srow] = p[2]; xs[scol + 3][srow] = p[3];
            const float* q0 = (const float*)&rc0;
            cs[scol + 0][srow] = q0[0]; cs[scol + 1][srow] = q0[1];
            cs[scol + 2][srow] = q0[2]; cs[scol + 3][srow] = q0[3];
            const float* q1 = (const float*)&rc1;
            cs[scol + 0][srow + 64] = q1[0]; cs[scol + 1][srow + 64] = q1[1];
            cs[scol + 2][srow + 64] = q1[2]; cs[scol + 3][srow + 64] = q1[3];
            __syncthreads();
            if (k0 + 16 < DD) {
                rx  = *(const float4*)(xg + k0 + 16);
                rc0 = *(const float4*)(cgA + nOff + k0 + 16);
                rc1 = *(const float4*)(cgB + nOff + k0 + 16);
            }
#pragma unroll
            for (int dd = 0; dd < 16; ++dd) {
                float4 av  = *(const float4*)&xs[dd][ty << 2];
                float4 bv0 = *(const float4*)&cs[dd][tx << 2];
                float4 bv1 = *(const float4*)&cs[dd][64 + (tx << 2)];
                const float* a  = (const float*)&av;
                const float* b0 = (const float*)&bv0;
                const float* b1 = (const float*)&bv1;
#pragma unroll
                for (int i = 0; i < 4; ++i)
#pragma unroll
                    for (int j = 0; j < 4; ++j) {
                        acc[i][0][j] = fmaf(a[i], b0[j], acc[i][0][j]);
                        acc[i][1][j] = fmaf(a[i], b1[j], acc[i][1][j]);
                    }
            }
        }
        float4 qv0 = *(const float4*)(csq + n0 + (tx << 2));
        float4 qv1 = *(const float4*)(csq + n0 + 64 + (tx << 2));
        const float* q0 = (const float*)&qv0;
        const float* q1 = (const float*)&qv1;
#pragma unroll
        for (int i = 0; i < 4; ++i)
#pragma unroll
            for (int h = 0; h < 2; ++h)
#pragma unroll
                for (int j = 0; j < 4; ++j) {
                    float qq = (h == 0) ? q0[j] : q1[j];
                    float dist = fmaf(-2.f, acc[i][h][j], qq);
                    int kk = n0 + h * 64 + (tx << 2) + j;
                    if (dist < best[i] || (dist == best[i] && kk < bidx[i])) {
                        best[i] = dist; bidx[i] = kk;
                    }
                }
    }
#pragma unroll
    for (int off = 1; off < 16; off <<= 1)
#pragma unroll
        for (int i = 0; i < 4; ++i) {
            float ov = __shfl_xor(best[i], off, 64);
            int oi = __shfl_xor(bidx[i], off, 64);
            if (ov < best[i] || (ov == best[i] && oi < bidx[i])) {
                best[i] = ov; bidx[i] = oi;
            }
        }
    if (tx == 0)
#pragma unroll
        for (int i = 0; i < 4; ++i) out[m0 + (ty << 2) + i] = bidx[i];
}

extern "C" void kernel_launch(void* const* d_in, const int* in_sizes, int n_in,
                              void* d_out, int out_size, void* d_ws, size_t ws_size,
                              hipStream_t stream) {
    const float* x    = (const float*)d_in[0];
    const float* cent = (const float*)d_in[1];
    int* out = (int*)d_out;

    const size_t xb_bytes     = (size_t)NB * DD * 2;   // 32MB (tiled)
    const size_t cb_bytes     = (size_t)KC * DD * 2;   // 4MB  (tiled)
    const size_t rowmin_bytes = (size_t)NB * 4;
    const size_t keys_bytes   = (size_t)NB * 8;
    const size_t csq_bytes    = (size_t)KC * 4;
    const size_t need = xb_bytes + cb_bytes + rowmin_bytes + keys_bytes + csq_bytes;

    if (ws_size >= need) {
        unsigned short* xbT = (unsigned short*)d_ws;
        unsigned short* cbT = (unsigned short*)((char*)d_ws + xb_bytes);
        unsigned* rowmin = (unsigned*)((char*)d_ws + xb_bytes + cb_bytes);
        unsigned long long* keys =
            (unsigned long long*)((char*)d_ws + xb_bytes + cb_bytes + rowmin_bytes);
        float* csq = (float*)((char*)d_ws + xb_bytes + cb_bytes + rowmin_bytes + keys_bytes);

        hipMemsetAsync(rowmin, 0xFF, rowmin_bytes, stream);
        hipMemsetAsync(keys, 0xFF, keys_bytes, stream);
        tile_bf16_kernel<<<NB * DD / 8 / 256, 256, 0, stream>>>(x, xbT);
        tile_bf16_kernel<<<KC * DD / 8 / 256, 256, 0, stream>>>(cent, cbT);
        csq_kernel<<<KC / 4, 256, 0, stream>>>(cent, csq);
        gemm_fast2<1><<<(NB / 128) * (KC / 128), 256, 0, stream>>>(
            xbT, cbT, x, cent, csq, rowmin, nullptr);
        gemm_fast2<2><<<(NB / 128) * (KC / 128), 256, 0, stream>>>(
            xbT, cbT, x, cent, csq, rowmin, keys);
        finalize_kernel<<<NB / 256, 256, 0, stream>>>(keys, out);
    } else {
        float* csq = (float*)d_ws;
        csq_kernel<<<KC / 4, 256, 0, stream>>>(cent, csq);
        argmin_fp32_kernel<<<NB / 64, 256, 0, stream>>>(x, cent, csq, out);
    }
}

// Round 5
// 1042.201 us; speedup vs baseline: 1.8255x; 1.1074x over previous
//
#include <hip/hip_runtime.h>
#include <math.h>

#define NB 32768
#define KC 4096
#define DD 512
#define DELTA 4.0f

typedef __attribute__((ext_vector_type(8))) short short8;
typedef __attribute__((ext_vector_type(4))) float facc4;

#define AS1 __attribute__((address_space(1)))
#define AS3 __attribute__((address_space(3)))

__device__ __forceinline__ void gll16(const void* g, void* lds) {
    __builtin_amdgcn_global_load_lds((const AS1 unsigned*)g, (AS3 unsigned*)lds,
                                     16, 0, 0);
}

__device__ __forceinline__ unsigned short f2bf(float f) {
    unsigned u = __float_as_uint(f);
    u += 0x7FFFu + ((u >> 16) & 1u);     // RNE
    return (unsigned short)(u >> 16);
}
__device__ __forceinline__ unsigned ordenc(float f) {
    unsigned u = __float_as_uint(f);
    return (u & 0x80000000u) ? ~u : (u | 0x80000000u);
}
__device__ __forceinline__ float orddec(unsigned o) {
    unsigned u = (o & 0x80000000u) ? (o & 0x7FFFFFFFu) : ~o;
    return __uint_as_float(u);
}

// ---- fp32 -> bf16 convert + tile to [blk][kstep][128 r][64 d] (LDS image) ----
__global__ __launch_bounds__(256) void tile_bf16_kernel(const float* __restrict__ in,
                                                        unsigned short* __restrict__ out) {
    const size_t t = (size_t)blockIdx.x * 256 + threadIdx.x;
    const int row = (int)(t >> 6);
    const int d0  = (int)(t & 63) << 3;
    const int blk = row >> 7, r = row & 127;
    const int ks  = d0 >> 6,  dw = d0 & 63;
    const float4* p = (const float4*)(in + (size_t)row * DD + d0);
    float4 a = p[0], b = p[1];
    unsigned q0 = (unsigned)f2bf(a.x) | ((unsigned)f2bf(a.y) << 16);
    unsigned q1 = (unsigned)f2bf(a.z) | ((unsigned)f2bf(a.w) << 16);
    unsigned q2 = (unsigned)f2bf(b.x) | ((unsigned)f2bf(b.y) << 16);
    unsigned q3 = (unsigned)f2bf(b.z) | ((unsigned)f2bf(b.w) << 16);
    const size_t o = (((size_t)blk * 8 + ks) * 128 + r) * 64 + dw;
    *(uint4*)(out + o) = make_uint4(q0, q1, q2, q3);
}

// ---------------- c_sq[k] = sum_d c[k][d]^2 (fp32) ----------------
__global__ __launch_bounds__(256) void csq_kernel(const float* __restrict__ cent,
                                                  float* __restrict__ csq) {
    const int wid  = threadIdx.x >> 6;
    const int lane = threadIdx.x & 63;
    const int k = (blockIdx.x << 2) + wid;
    const float* row = cent + (size_t)k * DD;
    float s = 0.f;
#pragma unroll
    for (int d = 0; d < DD; d += 64) {
        float v = row[d + lane];
        s = fmaf(v, v, s);
    }
#pragma unroll
    for (int off = 32; off > 0; off >>= 1) s += __shfl_xor(s, off, 64);
    if (lane == 0) csq[k] = s;
}

// ---------------- exact fp32 rescue for one (row, col) ----------------
__device__ __noinline__ void rescue(const float* __restrict__ x,
                                    const float* __restrict__ cent,
                                    const float* __restrict__ csq,
                                    unsigned long long* __restrict__ keyr,
                                    int r, int k) {
    const float4* xr = (const float4*)(x + (size_t)r * DD);
    const float4* ck = (const float4*)(cent + (size_t)k * DD);
    float s0 = 0.f, s1 = 0.f, s2 = 0.f, s3 = 0.f;
    for (int d = 0; d < DD / 4; ++d) {
        float4 a = xr[d];
        float4 b = ck[d];
        s0 = fmaf(a.x, b.x, s0);
        s1 = fmaf(a.y, b.y, s1);
        s2 = fmaf(a.z, b.z, s2);
        s3 = fmaf(a.w, b.w, s3);
    }
    float dist = fmaf(-2.f, (s0 + s1) + (s2 + s3), csq[k]);
    unsigned long long key = ((unsigned long long)ordenc(dist) << 32) | (unsigned)k;
    atomicMin(keyr, key);
}

// ------ m97-exact single-buffer bf16 MFMA GEMM on pre-tiled operands ------
// 128x128 tile, BK=64, 32KB LDS -> 4 blocks/CU resident (inter-block overlap
// per m114 does the latency hiding; explicit dbuf regressed occupancy, m132).
template <int PASS>
__global__ __launch_bounds__(256) void gemm_fast3(
    const unsigned short* __restrict__ xbT, const unsigned short* __restrict__ cbT,
    const float* __restrict__ x, const float* __restrict__ cent,
    const float* __restrict__ csq, unsigned* __restrict__ rowmin,
    unsigned long long* __restrict__ keys)
{
    __shared__ unsigned short Ab[8192];   // 16KB
    __shared__ unsigned short Bb[8192];   // 16KB

    const int tid = threadIdx.x;
    const int l = tid & 63, w = tid >> 6;
    const int wr = w >> 1, wc = w & 1;

    // XCD map: xcd = bid&7 owns 4 nblk columns; mblk streams fastest so the
    // 128KB B tile stays hot in the XCD-private L2; A tiles stream from L3.
    const int bid = blockIdx.x;
    const int i   = bid >> 3;                  // 0..1023
    const int nblk = (bid & 7) * 4 + (i >> 8); // 0..31
    const int mblk = i & 255;                  // 0..255
    const int m0 = mblk * 128, n0 = nblk * 128;

    // staging: wave w copies quarter-tile (4KB) as 4 contiguous 1KB gll16
    const unsigned short* ga = xbT + (size_t)mblk * 8 * 8192 + w * 2048 + l * 8;
    const unsigned short* gb = cbT + (size_t)nblk * 8 * 8192 + w * 2048 + l * 8;

    // fragment read addressing (validated rounds 2-4), linear LDS [row][64]
    const int hi = l >> 4, ln = l & 15;

    float rm[4][4];
    float thr[4][4];
    if (PASS == 1) {
#pragma unroll
        for (int fr = 0; fr < 4; ++fr)
#pragma unroll
            for (int j = 0; j < 4; ++j) rm[fr][j] = INFINITY;
    } else {
#pragma unroll
        for (int fr = 0; fr < 4; ++fr)
#pragma unroll
            for (int j = 0; j < 4; ++j)
                thr[fr][j] = orddec(rowmin[m0 + wr * 64 + fr * 16 + hi * 4 + j]) + DELTA;
    }

    facc4 acc[4][4];
#pragma unroll
    for (int fr = 0; fr < 4; ++fr)
#pragma unroll
        for (int fc = 0; fc < 4; ++fc) {
            facc4 z = {0.f, 0.f, 0.f, 0.f};
            acc[fr][fc] = z;
        }

#pragma unroll 1
    for (int ks = 0; ks < 8; ++ks) {
        // ---- stage both 128x64 bf16 tiles: 8 async 1KB-contiguous issues ----
        const unsigned short* sa = ga + (size_t)ks * 8192;
        const unsigned short* sb = gb + (size_t)ks * 8192;
#pragma unroll
        for (int q = 0; q < 4; ++q) {
            gll16(sa + q * 512, &Ab[w * 2048 + q * 512]);
            gll16(sb + q * 512, &Bb[w * 2048 + q * 512]);
        }
        __syncthreads();   // drains vmcnt; inter-block overlap hides this

        // ---- 2 x (8 ds_read_b128 + 16 MFMA) ----
#pragma unroll
        for (int kk = 0; kk < 2; ++kk) {
            const int ko = (kk * 4 + hi) * 8;
            short8 av[4], bv[4];
#pragma unroll
            for (int fr = 0; fr < 4; ++fr)
                av[fr] = *(const short8*)&Ab[(wr * 64 + fr * 16 + ln) * 64 + ko];
#pragma unroll
            for (int fc = 0; fc < 4; ++fc)
                bv[fc] = *(const short8*)&Bb[(wc * 64 + fc * 16 + ln) * 64 + ko];
#pragma unroll
            for (int fr = 0; fr < 4; ++fr)
#pragma unroll
                for (int fc = 0; fc < 4; ++fc)
                    acc[fr][fc] = __builtin_amdgcn_mfma_f32_16x16x32_bf16(
                        av[fr], bv[fc], acc[fr][fc], 0, 0, 0);
        }
        __syncthreads();   // protect LDS before next stage
    }

    // ---- epilogue: dist = csq[col] - 2*acc (validated) ----
#pragma unroll
    for (int fc = 0; fc < 4; ++fc) {
        const int col = n0 + wc * 64 + fc * 16 + ln;
        const float q = csq[col];
#pragma unroll
        for (int fr = 0; fr < 4; ++fr)
#pragma unroll
            for (int j = 0; j < 4; ++j) {
                const float dist = fmaf(-2.f, acc[fr][fc][j], q);
                if (PASS == 1) {
                    rm[fr][j] = fminf(rm[fr][j], dist);
                } else {
                    if (dist <= thr[fr][j]) {
                        const int row = m0 + wr * 64 + fr * 16 + hi * 4 + j;
                        rescue(x, cent, csq, keys + row, row, col);
                    }
                }
            }
    }

    if (PASS == 1) {
#pragma unroll
        for (int off = 1; off < 16; off <<= 1)
#pragma unroll
            for (int fr = 0; fr < 4; ++fr)
#pragma unroll
                for (int j = 0; j < 4; ++j)
                    rm[fr][j] = fminf(rm[fr][j], __shfl_xor(rm[fr][j], off, 64));
        if (ln == 0) {
#pragma unroll
            for (int fr = 0; fr < 4; ++fr)
#pragma unroll
                for (int j = 0; j < 4; ++j)
                    atomicMin(&rowmin[m0 + wr * 64 + fr * 16 + hi * 4 + j],
                              ordenc(rm[fr][j]));
        }
    }
}

__global__ __launch_bounds__(256) void finalize_kernel(
        const unsigned long long* __restrict__ keys, int* __restrict__ out) {
    const int i = blockIdx.x * 256 + threadIdx.x;
    out[i] = (int)(keys[i] & 0xFFFFFFFFull);
}

// ---------------- fallback: round-1 fp32 kernel (proven) ----------------
__global__ __launch_bounds__(256) void argmin_fp32_kernel(
        const float* __restrict__ x, const float* __restrict__ cent,
        const float* __restrict__ csq, int* __restrict__ out) {
    __shared__ float xs[16][68];
    __shared__ float cs[16][132];
    const int tid = threadIdx.x;
    const int tx = tid & 15;
    const int ty = tid >> 4;
    const int m0 = blockIdx.x * 64;
    const int srow = tid >> 2;
    const int scol = (tid & 3) << 2;
    const float* xg  = x + (size_t)(m0 + srow) * DD + scol;
    const float* cgA = cent + (size_t)srow * DD + scol;
    const float* cgB = cent + (size_t)(srow + 64) * DD + scol;
    float best[4];
    int bidx[4];
#pragma unroll
    for (int i = 0; i < 4; ++i) { best[i] = INFINITY; bidx[i] = 0; }
    for (int n0 = 0; n0 < KC; n0 += 128) {
        float acc[4][2][4];
#pragma unroll
        for (int i = 0; i < 4; ++i)
#pragma unroll
            for (int h = 0; h < 2; ++h)
#pragma unroll
                for (int j = 0; j < 4; ++j) acc[i][h][j] = 0.f;
        const size_t nOff = (size_t)n0 * DD;
        float4 rx = *(const float4*)(xg);
        float4 rc0 = *(const float4*)(cgA + nOff);
        float4 rc1 = *(const float4*)(cgB + nOff);
        for (int k0 = 0; k0 < DD; k0 += 16) {
            __syncthreads();
            const float* p = (const float*)&rx;
            xs[scol + 0][srow] = p[0]; xs[scol + 1][srow] = p[1];
            xs[scol + 2][srow] = p[2]; xs[scol + 3][srow] = p[3];
            const float* q0 = (const float*)&rc0;
            cs[scol + 0][srow] = q0[0]; cs[scol + 1][srow] = q0[1];
            cs[scol + 2][srow] = q0[2]; cs[scol + 3][srow] = q0[3];
            const float* q1 = (const float*)&rc1;
            cs[scol + 0][srow + 64] = q1[0]; cs[scol + 1][srow + 64] = q1[1];
            cs[scol + 2][srow + 64] = q1[2]; cs[scol + 3][srow + 64] = q1[3];
            __syncthreads();
            if (k0 + 16 < DD) {
                rx  = *(const float4*)(xg + k0 + 16);
                rc0 = *(const float4*)(cgA + nOff + k0 + 16);
                rc1 = *(const float4*)(cgB + nOff + k0 + 16);
            }
#pragma unroll
            for (int dd = 0; dd < 16; ++dd) {
                float4 av  = *(const float4*)&xs[dd][ty << 2];
                float4 bv0 = *(const float4*)&cs[dd][tx << 2];
                float4 bv1 = *(const float4*)&cs[dd][64 + (tx << 2)];
                const float* a  = (const float*)&av;
                const float* b0 = (const float*)&bv0;
                const float* b1 = (const float*)&bv1;
#pragma unroll
                for (int i = 0; i < 4; ++i)
#pragma unroll
                    for (int j = 0; j < 4; ++j) {
                        acc[i][0][j] = fmaf(a[i], b0[j], acc[i][0][j]);
                        acc[i][1][j] = fmaf(a[i], b1[j], acc[i][1][j]);
                    }
            }
        }
        float4 qv0 = *(const float4*)(csq + n0 + (tx << 2));
        float4 qv1 = *(const float4*)(csq + n0 + 64 + (tx << 2));
        const float* q0 = (const float*)&qv0;
        const float* q1 = (const float*)&qv1;
#pragma unroll
        for (int i = 0; i < 4; ++i)
#pragma unroll
            for (int h = 0; h < 2; ++h)
#pragma unroll
                for (int j = 0; j < 4; ++j) {
                    float qq = (h == 0) ? q0[j] : q1[j];
                    float dist = fmaf(-2.f, acc[i][h][j], qq);
                    int kk = n0 + h * 64 + (tx << 2) + j;
                    if (dist < best[i] || (dist == best[i] && kk < bidx[i])) {
                        best[i] = dist; bidx[i] = kk;
                    }
                }
    }
#pragma unroll
    for (int off = 1; off < 16; off <<= 1)
#pragma unroll
        for (int i = 0; i < 4; ++i) {
            float ov = __shfl_xor(best[i], off, 64);
            int oi = __shfl_xor(bidx[i], off, 64);
            if (ov < best[i] || (ov == best[i] && oi < bidx[i])) {
                best[i] = ov; bidx[i] = oi;
            }
        }
    if (tx == 0)
#pragma unroll
        for (int i = 0; i < 4; ++i) out[m0 + (ty << 2) + i] = bidx[i];
}

extern "C" void kernel_launch(void* const* d_in, const int* in_sizes, int n_in,
                              void* d_out, int out_size, void* d_ws, size_t ws_size,
                              hipStream_t stream) {
    const float* x    = (const float*)d_in[0];
    const float* cent = (const float*)d_in[1];
    int* out = (int*)d_out;

    const size_t xb_bytes     = (size_t)NB * DD * 2;   // 32MB (tiled)
    const size_t cb_bytes     = (size_t)KC * DD * 2;   // 4MB  (tiled)
    const size_t rowmin_bytes = (size_t)NB * 4;
    const size_t keys_bytes   = (size_t)NB * 8;
    const size_t csq_bytes    = (size_t)KC * 4;
    const size_t need = xb_bytes + cb_bytes + rowmin_bytes + keys_bytes + csq_bytes;

    if (ws_size >= need) {
        unsigned short* xbT = (unsigned short*)d_ws;
        unsigned short* cbT = (unsigned short*)((char*)d_ws + xb_bytes);
        unsigned* rowmin = (unsigned*)((char*)d_ws + xb_bytes + cb_bytes);
        unsigned long long* keys =
            (unsigned long long*)((char*)d_ws + xb_bytes + cb_bytes + rowmin_bytes);
        float* csq = (float*)((char*)d_ws + xb_bytes + cb_bytes + rowmin_bytes + keys_bytes);

        hipMemsetAsync(rowmin, 0xFF, rowmin_bytes, stream);
        hipMemsetAsync(keys, 0xFF, keys_bytes, stream);
        tile_bf16_kernel<<<NB * DD / 8 / 256, 256, 0, stream>>>(x, xbT);
        tile_bf16_kernel<<<KC * DD / 8 / 256, 256, 0, stream>>>(cent, cbT);
        csq_kernel<<<KC / 4, 256, 0, stream>>>(cent, csq);
        gemm_fast3<1><<<(NB / 128) * (KC / 128), 256, 0, stream>>>(
            xbT, cbT, x, cent, csq, rowmin, nullptr);
        gemm_fast3<2><<<(NB / 128) * (KC / 128), 256, 0, stream>>>(
            xbT, cbT, x, cent, csq, rowmin, keys);
        finalize_kernel<<<NB / 256, 256, 0, stream>>>(keys, out);
    } else {
        float* csq = (float*)d_ws;
        csq_kernel<<<KC / 4, 256, 0, stream>>>(cent, csq);
        argmin_fp32_kernel<<<NB / 64, 256, 0, stream>>>(x, cent, csq, out);
    }
}